// Round 1
// 196.798 us; speedup vs baseline: 1.0835x; 1.0835x over previous
//
#include <hip/hip_runtime.h>
#include <math.h>

// RBF-kernel causal attention (gfx950), round 6.
// Prepass: K -> f16 row-major + ksq(=s*|k|^2); V -> bf16 transposed
//          tile-contiguous Vt[bh][jt][128d][64j]. All fully coalesced.
// Main (v6): one 64-row Q-tile per block, 4 waves x 16 q-rows each --
//          every wave active every j-iteration (no intra-block idle).
//          Grid 32x32=1024 blocks, big tiles launched first; LDS cut to
//          45.3KB -> 3 blocks/CU (12 waves/CU vs ~4.2 effective before).
//          K/V staged in LDS (single buffer, reg-prefetch, 2 barriers/tile),
//          P transits wave-private LDS (no barrier needed).
//          setprio around MFMA clusters; v_cvt_pk_bf16_f32 for P pack.

#define NSEQ 2048
#define DH   128
#define BHC  32
#define SM_SCALE 0.08838834764831845f

typedef __attribute__((ext_vector_type(8))) short    short8;   // bf16x8
typedef __attribute__((ext_vector_type(8))) _Float16 half8;    // f16x8
typedef __attribute__((ext_vector_type(4))) short    short4_;
typedef __attribute__((ext_vector_type(4))) float    float4_;
typedef __attribute__((ext_vector_type(4))) unsigned uint4_;
typedef __attribute__((ext_vector_type(2))) unsigned uint2_;

#define KST 136   // K LDS row stride (shorts)
#define VST 72    // V^T LDS row stride (shorts)
#define PST 72    // P LDS row stride (shorts)

__device__ __forceinline__ short f2bf(float x){
  union{float f; unsigned u;} a; a.f=x;
  unsigned r = a.u + 0x7fffu + ((a.u>>16)&1u);   // RNE
  return (short)(r>>16);
}
__device__ __forceinline__ float bf2f(short h){
  union{float f; unsigned u;} a; a.u=((unsigned)(unsigned short)h)<<16; return a.f;
}
__device__ __forceinline__ unsigned packbf(float a, float b){
  return (unsigned)(unsigned short)f2bf(a) | ((unsigned)(unsigned short)f2bf(b)<<16);
}
__device__ __forceinline__ unsigned cvtpk_bf16(float a, float b){
  unsigned r;
  asm("v_cvt_pk_bf16_f32 %0, %1, %2" : "=v"(r) : "v"(a), "v"(b));
  return r;   // lo16 = bf16(a), hi16 = bf16(b), RNE
}

// ---------------- prepass ----------------
__global__ __launch_bounds__(256)
void prep_kv5(const float* __restrict__ kg, const float* __restrict__ vg,
              _Float16* __restrict__ khg, short* __restrict__ vtg,
              float* __restrict__ ksqg){
  __shared__ unsigned Vls[128*33];   // [d][j2] short2-pairs, stride 33 dw
  const int b = blockIdx.x, t = threadIdx.x;
  const int l = t & 63, wv = t >> 6;
  if(b < 1024){
    // ---- V tile (bh, jt): fp32 rows -> bf16 V^T tile-contiguous ----
    const int bh = b>>5, jt = b&31;
    const float4_* vb4 = (const float4_*)(vg + ((size_t)bh*NSEQ + (size_t)jt*64)*DH);
    #pragma unroll
    for(int i=0;i<8;++i){
      // linear-coalesced: f4 = i*256+t -> row = 8i + (t>>5), d = 4*(t&31)
      float4_ own = vb4[i*256 + t];
      float4_ par;
      par.x = __shfl_xor(own.x, 32); par.y = __shfl_xor(own.y, 32);
      par.z = __shfl_xor(own.z, 32); par.w = __shfl_xor(own.w, 32);
      const int hi = (l>>5)&1;           // row-parity bit
      unsigned w0 = hi ? packbf(par.z, own.z) : packbf(own.x, par.x);
      unsigned w1 = hi ? packbf(par.w, own.w) : packbf(own.y, par.y);
      const int dd = 4*(t&31) + 2*hi;
      const int j2 = 4*i + wv;           // row-pair index
      Vls[dd*33 + j2]     = w0;
      Vls[(dd+1)*33 + j2] = w1;
    }
    __syncthreads();
    short* outp = vtg + ((size_t)(bh*32 + jt)*DH)*64;
    #pragma unroll
    for(int it=0; it<4; ++it){
      int idx = t + 256*it;              // 0..1023
      int d = idx>>3, slot = idx&7;
      uint4_ o;
      o.x = Vls[d*33 + 4*slot];   o.y = Vls[d*33 + 4*slot+1];
      o.z = Vls[d*33 + 4*slot+2]; o.w = Vls[d*33 + 4*slot+3];
      *(uint4_*)(outp + d*64 + 8*slot) = o;
    }
  } else {
    // ---- K: fp32 -> f16 row-major + ksq ----
    const int kb = b - 1024;             // 64 rows per block
    const float4_* kb4 = (const float4_*)(kg + (size_t)kb*64*DH);
    #pragma unroll
    for(int i=0;i<8;++i){
      float4_ x = kb4[i*256 + t];        // row = 64kb + 8i + (t>>5), d = 4*(t&31)
      const int row = 64*kb + 8*i + (t>>5);
      const int d   = 4*(t&31);
      union{ _Float16 h[4]; uint2_ u; } pk;
      pk.h[0]=(_Float16)x.x; pk.h[1]=(_Float16)x.y;
      pk.h[2]=(_Float16)x.z; pk.h[3]=(_Float16)x.w;
      *(uint2_*)(khg + (size_t)row*DH + d) = pk.u;
      float ss = x.x*x.x + x.y*x.y + x.z*x.z + x.w*x.w;
      ss += __shfl_xor(ss,1);  ss += __shfl_xor(ss,2);
      ss += __shfl_xor(ss,4);  ss += __shfl_xor(ss,8);
      ss += __shfl_xor(ss,16);
      if((l&31)==0) ksqg[row] = SM_SCALE*ss;
    }
  }
}

// ---------------- main kernel (v6) ----------------
__global__ __launch_bounds__(256,3)
void rbf_attn6(const float* __restrict__ qg,
               const _Float16* __restrict__ khg,
               const short* __restrict__ vtg,
               const float* __restrict__ ksqg,
               float* __restrict__ og){
  __shared__ short Kst[64*KST];    // 17408 B (f16 bits)
  __shared__ short Vst[128*VST];   // 18432 B (bf16)
  __shared__ short Pls[4*16*PST];  //  9216 B wave-private P (16 rows/wave)
  __shared__ float ksLs[64];
  // total 45,312 B -> 3 blocks/CU

  const int tid=threadIdx.x;
  const int w=tid>>6, l=tid&63;
  const int quad=l>>4, lr=l&15;
  const int bh=blockIdx.x;
  const int mq = 31 - blockIdx.y;        // big Q-tiles dispatch first
  const int qbase = 64*mq + 16*w;        // wave owns 16 q-rows

  const float*    Qg = qg   + (size_t)bh*NSEQ*DH;
  const _Float16* Kh = khg  + (size_t)bh*NSEQ*DH;
  const short*    Vt = vtg  + (size_t)bh*32*DH*64;
  const float*    Ks = ksqg + (size_t)bh*NSEQ;
  float*          Og = og   + (size_t)bh*NSEQ*DH;
  short* Pw = Pls + w*16*PST;

  // ---- Q -> f16 B-fragments (once) + qsq ----
  half8 qf[4];
  float qsq;
  {
    const int qrow = qbase + lr;
    const float* qp = Qg + (size_t)qrow*DH + 8*quad;
    float ss=0.f;
    #pragma unroll
    for(int ks=0;ks<4;++ks){
      float4_ a = *(const float4_*)(qp + 32*ks);
      float4_ b = *(const float4_*)(qp + 32*ks + 4);
      half8 h;
      #pragma unroll
      for(int j=0;j<4;++j){
        h[j]   = (_Float16)a[j];
        h[j+4] = (_Float16)b[j];
        ss += a[j]*a[j] + b[j]*b[j];
      }
      qf[ks]=h;
    }
    ss += __shfl_xor(ss,16);
    ss += __shfl_xor(ss,32);
    qsq = SM_SCALE*ss;
  }

  float4_ oacc[8];
  #pragma unroll
  for(int b2=0;b2<8;++b2) oacc[b2] = (float4_)0.f;

  // ---- staging prefetch regs for jt=0 ----
  uint4_ kreg[4], vreg[4];
  float  kqreg = 0.f;
  {
    #pragma unroll
    for(int it=0;it<4;++it){
      int idx = tid + 256*it;
      int row = idx>>4, c = idx&15;
      kreg[it] = *(const uint4_*)(Kh + (size_t)row*DH + 8*c);
      int d = idx>>3, slot = idx&7;
      vreg[it] = *(const uint4_*)(Vt + (size_t)d*64 + 8*slot);
    }
    if(tid<64) kqreg = Ks[tid];
  }

  for(int jt=0; jt<=mq; ++jt){
    // ---- write staged regs -> LDS ----
    #pragma unroll
    for(int it=0;it<4;++it){
      int idx = tid + 256*it;
      int row = idx>>4, c = idx&15;
      *(uint4_*)&Kst[row*KST + 8*c] = kreg[it];
      int d = idx>>3, slot = idx&7;
      *(uint4_*)&Vst[d*VST + 8*slot] = vreg[it];
    }
    if(tid<64) ksLs[tid] = kqreg;
    __syncthreads();                       // B2: tile visible

    // ---- prefetch next tile -> regs ----
    if(jt < mq){
      const int jc2 = (jt+1)*64;
      #pragma unroll
      for(int it=0;it<4;++it){
        int idx = tid + 256*it;
        int row = idx>>4, c = idx&15;
        kreg[it] = *(const uint4_*)(Kh + (size_t)(jc2+row)*DH + 8*c);
        int d = idx>>3, slot = idx&7;
        vreg[it] = *(const uint4_*)(Vt + ((size_t)(jt+1)*DH + d)*64 + 8*slot);
      }
      if(tid<64) kqreg = Ks[jc2 + tid];
    }

    // ---- S^T = K . Q^T (f16, single pass) ----
    float4_ sacc[4];
    #pragma unroll
    for(int ct=0;ct<4;++ct) sacc[ct] = (float4_)0.f;

    __builtin_amdgcn_s_setprio(1);
    #pragma unroll
    for(int ks=0;ks<4;++ks){
      half8 kf[4];
      #pragma unroll
      for(int ct=0;ct<4;++ct)
        kf[ct] = *(const half8*)&Kst[(16*ct+lr)*KST + 32*ks + 8*quad];
      #pragma unroll
      for(int ct=0;ct<4;++ct)
        sacc[ct]=__builtin_amdgcn_mfma_f32_16x16x32_f16(kf[ct],qf[ks],sacc[ct],0,0,0);
    }
    __builtin_amdgcn_s_setprio(0);

    // ---- exp -> bf16 P (wave-private LDS, no barrier) ----
    {
      const int jg0 = 64*jt;
      const int qrow = qbase + lr;
      #pragma unroll
      for(int ct=0;ct<4;++ct){
        float4_ kq = *(const float4_*)&ksLs[16*ct + 4*quad];
        const int j0 = jg0 + 16*ct + 4*quad;
        float p[4];
        #pragma unroll
        for(int r=0;r<4;++r){
          float logit = (2.f*SM_SCALE)*sacc[ct][r] - qsq - kq[r];
          p[r] = (j0 + r <= qrow) ? __expf(logit) : 0.f;
        }
        uint2_ pw;
        pw.x = cvtpk_bf16(p[0], p[1]);
        pw.y = cvtpk_bf16(p[2], p[3]);
        *(uint2_*)&Pw[lr*PST + 16*ct + 4*quad] = pw;
      }
    }

    // ---- O += P . V ----
    __builtin_amdgcn_s_setprio(1);
    #pragma unroll
    for(int ks2=0;ks2<2;++ks2){
      const short8 pf = *(const short8*)&Pw[lr*PST + 32*ks2 + 8*quad];
      #pragma unroll
      for(int ctv=0;ctv<8;++ctv){
        const short8 vf = *(const short8*)&Vst[(16*ctv+lr)*VST + 32*ks2 + 8*quad];
        oacc[ctv]=__builtin_amdgcn_mfma_f32_16x16x32_bf16(pf,vf,oacc[ctv],0,0,0);
      }
    }
    __builtin_amdgcn_s_setprio(0);

    __syncthreads();                       // B1: reads done before overwrite
  }

  // ---- store O ----
  #pragma unroll
  for(int ctv=0;ctv<8;++ctv)
    #pragma unroll
    for(int r=0;r<4;++r){
      const int qrow = qbase + 4*quad + r;
      Og[(size_t)qrow*DH + 16*ctv + lr] = oacc[ctv][r];
    }
}

// ---------------- fallback (no-workspace path, verified R2 kernel) ----------------
#define KSTf 136
#define VSTf 36
#define PSTf 72

__global__ __launch_bounds__(256,2)
void rbf_attn_mfma(const float* __restrict__ qg, const float* __restrict__ kg,
                   const float* __restrict__ vg, float* __restrict__ og){
  __shared__ short    Khi[64*KSTf];
  __shared__ short    Klo[64*KSTf];
  __shared__ unsigned VP [128*VSTf];
  __shared__ short    Pfb[64*PSTf];
  __shared__ float    qsq_s[64];
  __shared__ float    ksq_s[64];

  const int tid=threadIdx.x;
  const int w=tid>>6, l=tid&63;
  const int wr=w>>1, wc=w&1;
  const int quad=l>>4, lr=l&15;
  const int bh=blockIdx.x, yp=blockIdx.y;

  const float* Qg = qg + (size_t)bh*NSEQ*DH;
  const float* Kg = kg + (size_t)bh*NSEQ*DH;
  const float* Vg = vg + (size_t)bh*NSEQ*DH;
  float*       Og = og + (size_t)bh*NSEQ*DH;

  for(int pass=0;pass<2;++pass){
    const int m = pass ? (31-yp) : yp;
    __syncthreads();
    short8 qhf[2][4], qlf[2][4];
    #pragma unroll
    for(int rt=0;rt<2;++rt){
      const int grow = m*64 + 32*wr + 16*rt + lr;
      const float* qp = Qg + (size_t)grow*DH + 8*quad;
      float ss=0.f;
      #pragma unroll
      for(int ks=0;ks<4;++ks){
        float4_ a = *(const float4_*)(qp + 32*ks);
        float4_ b = *(const float4_*)(qp + 32*ks + 4);
        short8 hi, lo;
        #pragma unroll
        for(int j=0;j<4;++j){
          float fa=a[j], fb=b[j];
          short ha=f2bf(fa); hi[j]=ha;   lo[j]=f2bf(fa-bf2f(ha));
          short hb=f2bf(fb); hi[j+4]=hb; lo[j+4]=f2bf(fb-bf2f(hb));
          ss += fa*fa + fb*fb;
        }
        qhf[rt][ks]=hi; qlf[rt][ks]=lo;
      }
      ss += __shfl_xor(ss,16);
      ss += __shfl_xor(ss,32);
      if(wc==0 && quad==0) qsq_s[32*wr+16*rt+lr] = SM_SCALE*ss;
    }
    float4_ oacc[2][4];
    #pragma unroll
    for(int a=0;a<2;++a)
      #pragma unroll
      for(int b=0;b<4;++b) oacc[a][b] = (float4_)0.f;

    const int ntiles = m+1;
    for(int jt=0;jt<ntiles;++jt){
      const int jc = jt*64;
      __syncthreads();
      #pragma unroll
      for(int it=0;it<4;++it){
        const int i = tid + 256*it;
        const int row = i>>4, c0 = 8*(i&15);
        const float* kp = Kg + (size_t)(jc+row)*DH + c0;
        float4_ a = *(const float4_*)kp;
        float4_ b = *(const float4_*)(kp+4);
        short8 hi, lo;
        float ss=0.f;
        #pragma unroll
        for(int j=0;j<4;++j){
          float fa=a[j], fb=b[j];
          short ha=f2bf(fa); hi[j]=ha;   lo[j]=f2bf(fa-bf2f(ha));
          short hb=f2bf(fb); hi[j+4]=hb; lo[j+4]=f2bf(fb-bf2f(hb));
          ss += fa*fa + fb*fb;
        }
        ss += __shfl_xor(ss,1); ss += __shfl_xor(ss,2);
        ss += __shfl_xor(ss,4); ss += __shfl_xor(ss,8);
        if(lr==0) ksq_s[row] = SM_SCALE*ss;
        *(short8*)&Khi[row*KSTf + c0] = hi;
        *(short8*)&Klo[row*KSTf + c0] = lo;
      }
      #pragma unroll
      for(int it=0;it<4;++it){
        const int u = tid + 256*it;
        const int d = u & 127, jg = u >> 7;
        const float* vp = Vg + (size_t)(jc + 8*jg)*DH + d;
        float vv[8];
        #pragma unroll
        for(int jj=0;jj<8;++jj) vv[jj] = vp[(size_t)jj*DH];
        uint4_ pk;
        #pragma unroll
        for(int p2=0;p2<4;++p2)
          pk[p2] = (unsigned)(unsigned short)f2bf(vv[2*p2]) |
                   ((unsigned)(unsigned short)f2bf(vv[2*p2+1])<<16);
        *(uint4_*)&VP[d*VSTf + 4*jg] = pk;
      }
      __syncthreads();
      float4_ sacc[2][2];
      #pragma unroll
      for(int a=0;a<2;++a)
        #pragma unroll
        for(int b=0;b<2;++b) sacc[a][b] = (float4_)0.f;
      #pragma unroll
      for(int ks=0;ks<4;++ks){
        short8 khf[2], klf[2];
        #pragma unroll
        for(int ct=0;ct<2;++ct){
          const int off = (32*wc + 16*ct + lr)*KSTf + 32*ks + 8*quad;
          khf[ct] = *(const short8*)&Khi[off];
          klf[ct] = *(const short8*)&Klo[off];
        }
        #pragma unroll
        for(int rt=0;rt<2;++rt)
          #pragma unroll
          for(int ct=0;ct<2;++ct){
            sacc[rt][ct]=__builtin_amdgcn_mfma_f32_16x16x32_bf16(qhf[rt][ks],khf[ct],sacc[rt][ct],0,0,0);
            sacc[rt][ct]=__builtin_amdgcn_mfma_f32_16x16x32_bf16(qhf[rt][ks],klf[ct],sacc[rt][ct],0,0,0);
            sacc[rt][ct]=__builtin_amdgcn_mfma_f32_16x16x32_bf16(qlf[rt][ks],khf[ct],sacc[rt][ct],0,0,0);
          }
      }
      #pragma unroll
      for(int rt=0;rt<2;++rt){
        float qs[4];
        #pragma unroll
        for(int r=0;r<4;++r) qs[r]=qsq_s[32*wr+16*rt+4*quad+r];
        #pragma unroll
        for(int ct=0;ct<2;++ct){
          const float ksq = ksq_s[32*wc+16*ct+lr];
          const int colg = jc + 32*wc+16*ct+lr;
          #pragma unroll
          for(int r=0;r<4;++r){
            const int rowg = m*64 + 32*wr+16*rt+4*quad+r;
            float logit = (2.f*SM_SCALE)*sacc[rt][ct][r] - qs[r] - ksq;
            float p = (colg<=rowg)? __expf(logit) : 0.f;
            Pfb[(32*wr+16*rt+4*quad+r)*PSTf + 32*wc+16*ct+lr] = f2bf(p);
          }
        }
      }
      __syncthreads();
      #pragma unroll
      for(int ks2=0;ks2<2;++ks2){
        short8 pf[2];
        #pragma unroll
        for(int rt=0;rt<2;++rt)
          pf[rt] = *(const short8*)&Pfb[(32*wr+16*rt+lr)*PSTf + 32*ks2 + 8*quad];
        #pragma unroll
        for(int ctv=0;ctv<4;++ctv){
          const int d = 64*wc + 16*ctv + lr;
          const short8 vfb = *(const short8*)((const short*)VP + d*(2*VSTf) + 32*ks2 + 8*quad);
          #pragma unroll
          for(int rt=0;rt<2;++rt)
            oacc[rt][ctv]=__builtin_amdgcn_mfma_f32_16x16x32_bf16(pf[rt],vfb,oacc[rt][ctv],0,0,0);
        }
      }
    }
    #pragma unroll
    for(int rt=0;rt<2;++rt)
      #pragma unroll
      for(int ctv=0;ctv<4;++ctv)
        #pragma unroll
        for(int r=0;r<4;++r){
          const int rowg = m*64 + 32*wr + 16*rt + 4*quad + r;
          Og[(size_t)rowg*DH + 64*wc + 16*ctv + lr] = oacc[rt][ctv][r];
        }
  }
}

extern "C" void kernel_launch(void* const* d_in, const int* in_sizes, int n_in,
                              void* d_out, int out_size, void* d_ws, size_t ws_size,
                              hipStream_t stream) {
  const float* q = (const float*)d_in[0];
  const float* k = (const float*)d_in[1];
  const float* v = (const float*)d_in[2];
  float* out = (float*)d_out;

  const size_t nElem = (size_t)BHC*NSEQ*DH;            // 8.39M
  const size_t need  = nElem*2*sizeof(short) + (size_t)BHC*NSEQ*sizeof(float);

  if(ws_size >= need){
    _Float16* khg = (_Float16*)d_ws;
    short*    vtg = (short*)(khg + nElem);
    float*    ksqg = (float*)(vtg + nElem);
    prep_kv5<<<2048, 256, 0, stream>>>(k, v, khg, vtg, ksqg);
    rbf_attn6<<<dim3(BHC,32), 256, 0, stream>>>(q, khg, vtg, ksqg, out);
  } else {
    rbf_attn_mfma<<<dim3(BHC,16), 256, 0, stream>>>(q, k, v, out);
  }
}